// Round 22
// baseline (163.187 us; speedup 1.0000x reference)
//
#include <hip/hip_runtime.h>

#define N 4096
#define B 32
#define SST 66       // skew LDS row stride: 4-way scatter banks, b64-aligned conv reads
#define OST 34       // out-tile stride (overlaid on S)
#define SROWS 69     // logical skew rows -3..65 (band 0..62 consumed; 3 trash rows each side)
#define NP1 16641    // 129*129 P1 tiles  (= 8*2080+1)
#define Q1 2080
#define NP2 16129    // 127*127 P2 interior tiles (= 8*2016+1)
#define Q2 2016

// C(32,k) — binomial weights of (S+S^-1)^32; sum = 2^32 per pass.
__device__ constexpr float BIN32[33] = {
    1.f, 32.f, 496.f, 4960.f, 35960.f, 201376.f, 906192.f, 3365856.f,
    10518300.f, 28048800.f, 64512240.f, 129024480.f, 225792840.f,
    347373600.f, 471435600.f, 565722720.f, 601080390.f, 565722720.f,
    471435600.f, 347373600.f, 225792840.f, 129024480.f, 64512240.f,
    28048800.f, 10518300.f, 3365856.f, 906192.f, 201376.f, 35960.f,
    4960.f, 496.f, 32.f, 1.f};

// Bijective XCD-chunk swizzle (m204): HW assigns bid%8 -> XCD; each XCD owns a
// contiguous tile range so neighbor-tile halo re-reads hit the same per-XCD L2.
__device__ __forceinline__ int xcd_swz(int bid, int Q) {
    const int xcd = bid & 7;
    const int k = bid >> 3;
    return (xcd == 0) ? k : (Q + 1) + (xcd - 1) * Q + k;
}

// Half-sample mirror (replicate-pad iteration == free-space on this extension).
__device__ __forceinline__ int mir(int c) {
    c = (c < 0) ? (-1 - c) : c;
    return (c >= N) ? (2 * N - 1 - c) : c;
}

// bf16 RNE pack/unpack.
__device__ __forceinline__ unsigned short f2bf(float x) {
    unsigned b = __float_as_uint(x);
    b += 0x7FFFu + ((b >> 16) & 1u);
    return (unsigned short)(b >> 16);
}
__device__ __forceinline__ float bf2f(unsigned short u) {
    return __uint_as_float(((unsigned)u) << 16);
}

// Extended-t strips (tx>=4080 or ty>=4080) live in d_out (f32) at rows 64..128, cols <4064
// (disjoint from every P2-edge write, overwritten by P2-interior afterwards).
__device__ __forceinline__ size_t strip_off(int tx, int ty) {
    long e = (tx >= 4080) ? ((long)(ty + 16) * 32 + (tx - 4080))            // R1: 32x4128
                          : (132096L + (long)(ty - 4080) * (long)N + (tx + 16)); // R2: 4096x32
    return (size_t)(64 + e / 4064) * N + (size_t)(e % 4064);
}

// AO + modulate with precomputed diffuse (rx carries 2^64 deferred scale).
__device__ __forceinline__ float4 shade2(float4 v, float4 h, float4 df) {
    const float SC = 0x1p-64f;
    float4 o;
    o.x = df.x * (1.0f - fminf(fmaxf((v.x * SC - h.x) * 4.0f, 0.0f), 1.0f));
    o.y = df.y * (1.0f - fminf(fmaxf((v.y * SC - h.y) * 4.0f, 0.0f), 1.0f));
    o.z = df.z * (1.0f - fminf(fmaxf((v.z * SC - h.z) * 4.0f, 0.0f), 1.0f));
    o.w = df.w * (1.0f - fminf(fmaxf((v.w * SC - h.w) * 4.0f, 0.0f), 1.0f));
    return o;
}

// Chunked 33-tap conv on logical skew row d (phys row d+3): 2 chunks, 24-float windows.
__device__ __forceinline__ void conv33(const float* __restrict__ S, int rowAddr, float acc[8]) {
#pragma unroll
    for (int i = 0; i < 8; ++i) acc[i] = 0.f;
    {   // chunk 0: k = 0..15, window [0,24)
        float w[24];
#pragma unroll
        for (int j = 0; j < 12; ++j)
            *(float2*)&w[2 * j] = *(const float2*)&S[rowAddr + 2 * j];
#pragma unroll
        for (int k = 0; k < 16; ++k) {
            const float c = BIN32[k];
#pragma unroll
            for (int i = 0; i < 8; ++i) acc[i] = fmaf(c, w[i + k], acc[i]);
        }
    }
    {   // chunk 1: k = 16..32, window [16,40)
        float w[24];
#pragma unroll
        for (int j = 0; j < 12; ++j)
            *(float2*)&w[2 * j] = *(const float2*)&S[rowAddr + 16 + 2 * j];
#pragma unroll
        for (int k = 16; k <= 32; ++k) {
            const float c = BIN32[k];
#pragma unroll
            for (int i = 0; i < 8; ++i) acc[i] = fmaf(c, w[i + k - 16], acc[i]);
        }
    }
}

// ---------------- dif_stream: pure streaming normals -> bf16 diffuse ----------------
// Grid-stride, 2048 blocks: runs at HBM BW (no barriers, no LDS, nothing to wait on).
__global__ __launch_bounds__(256) void dif_stream(const float* __restrict__ nrm,
                                                  unsigned short* __restrict__ dif) {
    const float L0 = 0.7053f, L1 = -0.7053f, L2 = 0.7053f;
    const size_t NN = (size_t)N * N;
    const size_t stride = (size_t)gridDim.x * 256;
    for (size_t i = (size_t)blockIdx.x * 256 + threadIdx.x; i < NN / 4; i += stride) {
        const size_t base = 4 * i;
        const float4 n0 = *(const float4*)(nrm + base);
        const float4 n1 = *(const float4*)(nrm + NN + base);
        const float4 n2 = *(const float4*)(nrm + 2 * NN + base);
        ushort4 u;
        u.x = f2bf(fmaxf(n0.x * L0 + n1.x * L1 + n2.x * L2, 0.0f) * 0.3f + 0.7f);
        u.y = f2bf(fmaxf(n0.y * L0 + n1.y * L1 + n2.y * L2, 0.0f) * 0.3f + 0.7f);
        u.z = f2bf(fmaxf(n0.z * L0 + n1.z * L1 + n2.z * L2, 0.0f) * 0.3f + 0.7f);
        u.w = f2bf(fmaxf(n0.w * L0 + n1.w * L1 + n2.w * L2, 0.0f) * 0.3f + 0.7f);
        *(ushort4*)(dif + base) = u;
    }
}

// ---------------- P1: anti-diagonal 33-tap pass (no dif tail) ----------------
__global__ __launch_bounds__(256, 8) void p1_antidiag(const float* __restrict__ src,
                                                      unsigned short* __restrict__ tcore,
                                                      float* __restrict__ tstrip) {
    __shared__ float S[SROWS * SST + 8];   // 18.2 KB; S2 overlaid after a barrier
    const int tile = xcd_swz((int)blockIdx.x, Q1);
    const int bx = tile % 129, by = tile / 129;
    const int X0 = 32 * bx - 16, Y0 = 32 * by - 16;   // t-tile origin (can be -16)
    const bool edgeT = (bx == 0) | (by == 0) | (bx == 128) | (by == 128);
    const int tid = (int)threadIdx.x;

    // stage f on [X0-16, X0+48) x [Y0-16, Y0+48), branchless skew-scatter (row = lx'+ly')
    for (int m = tid; m < 64 * 16; m += 256) {
        const int ly = m >> 4, lx4 = m & 15;
        const int lyp = ly - 16, lxp = 4 * lx4 - 16;
        float4 v;
        if (!edgeT) {
            v = *(const float4*)(src + (size_t)(Y0 + lyp) * N + (X0 + lxp));
        } else {
            const float* row = src + (size_t)mir(Y0 + lyp) * N;
            v = make_float4(row[mir(X0 + lxp)], row[mir(X0 + lxp + 1)],
                            row[mir(X0 + lxp + 2)], row[mir(X0 + lxp + 3)]);
        }
        const int r0 = lxp + lyp;                 // logical skew row of v.x
        if (r0 >= -3 && r0 <= 62) {               // 4 bare stores; trash rows absorb edges
            const int base = (r0 + 3) * SST + (lxp + 16);
            S[base]                 = v.x;
            S[base + (SST + 1)]     = v.y;
            S[base + 2 * (SST + 1)] = v.z;
            S[base + 3 * (SST + 1)] = v.w;
        }
    }
    __syncthreads();

    // conv: thread (d=tid>>2, h=tid&3), taps contiguous in phys row d+3
    const int d = tid >> 2, h = tid & 3;
    const int lo = max(0, d - 31), hi = min(31, d);
    const int L = (lo & ~3) + 8 * h;
    const bool act = (d <= 62) && (L <= hi);
    float acc[8];
    if (act) conv33(S, (d + 3) * SST + L, acc);
    __syncthreads();                               // all S reads done; overlay S2

    float* SO = S;                                 // out-tile overlay
    if (act) {
#pragma unroll
        for (int i = 0; i < 8; ++i) {
            const int lx = L + i;
            if (lx >= lo && lx <= hi) SO[(d - lx) * OST + lx] = acc[i];
        }
    }
    __syncthreads();

    // writeback t
    {
        const int ly = tid >> 3, lx4 = tid & 7;
        const float2 v01 = *(const float2*)&SO[ly * OST + 4 * lx4];
        const float2 v23 = *(const float2*)&SO[ly * OST + 4 * lx4 + 2];
        const int wcol = X0 + 4 * lx4 + 16;   // tx+16
        const int wrow = Y0 + ly + 16;        // ty+16
        if (wcol < N && wrow < N) {
            ushort4 u;
            u.x = f2bf(v01.x); u.y = f2bf(v01.y); u.z = f2bf(v23.x); u.w = f2bf(v23.y);
            *(ushort4*)(tcore + (size_t)wrow * N + wcol) = u;
        } else {
            const int ty = Y0 + ly;
            const float vv[4] = {v01.x, v01.y, v23.x, v23.y};
#pragma unroll
            for (int e = 0; e < 4; ++e) {
                const int tx = X0 + 4 * lx4 + e;
                tstrip[strip_off(tx, ty)] = vv[e];
            }
        }
    }
}

// ---------------- P2: diagonal 33-tap pass + fused shade (diffuse from bf16) ----------------
// STRIPS=0: interior tiles (1D grid, XCD-swizzled); STRIPS=1: edge band.
template <int STRIPS>
__global__ __launch_bounds__(256, 8) void p2_diag(const unsigned short* __restrict__ tcore,
                                                  const float* __restrict__ tstrip,
                                                  float* __restrict__ dst,
                                                  const float* __restrict__ xin,
                                                  const unsigned short* __restrict__ dif) {
    __shared__ float S[SROWS * SST + 8];
    int X0, Y0;
    if constexpr (STRIPS) {
        if (blockIdx.y == 0) { X0 = 4064; Y0 = 32 * (int)blockIdx.x; }
        else                 { X0 = 32 * (int)blockIdx.x; Y0 = 4064; }
    } else {
        const int tile = xcd_swz((int)blockIdx.x, Q2);
        X0 = 32 * (tile % 127); Y0 = 32 * (tile / 127);
    }
    const int tid = (int)threadIdx.x;

    // stage t on [X0-16, X0+48) x [Y0-16, Y0+48), branchless skew-scatter (row = lx'-ly'+31)
    for (int m = tid; m < 64 * 16; m += 256) {
        const int ly = m >> 4, lx4 = m & 15;
        const int lyp = ly - 16, lxp = 4 * lx4 - 16;
        float4 v;
        if constexpr (!STRIPS) {
            const ushort4 u = *(const ushort4*)(tcore + (size_t)(Y0 + lyp + 16) * N + (X0 + lxp + 16));
            v = make_float4(bf2f(u.x), bf2f(u.y), bf2f(u.z), bf2f(u.w));
        } else {
            const int ty = Y0 + lyp;
            float tmp[4];
#pragma unroll
            for (int e = 0; e < 4; ++e) {
                const int tx = X0 + lxp + e;
                tmp[e] = (tx < 4080 && ty < 4080)
                             ? bf2f(tcore[(size_t)(ty + 16) * N + (tx + 16)])
                             : tstrip[strip_off(tx, ty)];
            }
            v = make_float4(tmp[0], tmp[1], tmp[2], tmp[3]);
        }
        const int r0 = lxp - lyp + 31;            // logical skew row of v.x
        if (r0 >= -3 && r0 <= 62) {
            const int base = (r0 + 3) * SST + (lxp + 16);
            S[base]                 = v.x;
            S[base + (SST + 1)]     = v.y;
            S[base + 2 * (SST + 1)] = v.z;
            S[base + 3 * (SST + 1)] = v.w;
        }
    }
    __syncthreads();

    const int d = tid >> 2, h = tid & 3;
    const int lo = max(0, d - 31), hi = min(31, d);
    const int L = (lo & ~3) + 8 * h;
    const bool act = (d <= 62) && (L <= hi);
    float acc[8];
    if (act) conv33(S, (d + 3) * SST + L, acc);
    __syncthreads();

    float* SO = S;
    if (act) {
#pragma unroll
        for (int i = 0; i < 8; ++i) {
            const int lx = L + i;
            if (lx >= lo && lx <= hi) SO[(lx - d + 31) * OST + lx] = acc[i];
        }
    }
    __syncthreads();

    // writeback + fused shade (always in-bounds)
    {
        const int ly = tid >> 3, lx4 = tid & 7;
        const float2 v01 = *(const float2*)&SO[ly * OST + 4 * lx4];
        const float2 v23 = *(const float2*)&SO[ly * OST + 4 * lx4 + 2];
        const float4 v = make_float4(v01.x, v01.y, v23.x, v23.y);
        const size_t base = (size_t)(Y0 + ly) * N + X0 + 4 * lx4;
        const float4 h4 = *(const float4*)(xin + base);
        const ushort4 ud = *(const ushort4*)(dif + base);
        const float4 df = make_float4(bf2f(ud.x), bf2f(ud.y), bf2f(ud.z), bf2f(ud.w));
        *(float4*)(dst + base) = shade2(v, h4, df);
    }
}

extern "C" void kernel_launch(void* const* d_in, const int* in_sizes, int n_in,
                              void* d_out, int out_size, void* d_ws, size_t ws_size,
                              hipStream_t stream) {
    const float* x       = (const float*)d_in[0];
    const float* normals = (const float*)d_in[1];
    float* out = (float*)d_out;
    unsigned short* ws16 = (unsigned short*)d_ws;       // t core (bf16, 32 MB)
    unsigned short* dif  = ws16 + (size_t)N * N;        // diffuse (bf16, 32 MB)

    dim3 block(256);

    // Pure streaming: normals -> bf16 diffuse at HBM BW.
    dif_stream<<<dim3(2048), block, 0, stream>>>(normals, dif);
    // P1: t on [-16,4112)^2 (mirror-extended). XCD-swizzled 1D grid.
    p1_antidiag<<<dim3(NP1), block, 0, stream>>>(x, ws16, out);
    // P2 edge band (x0=4064 or y0=4064): strip-aware reads; writes only cols>=4064 / rows>=4064.
    p2_diag<1><<<dim3(128, 2), block, 0, stream>>>(ws16, out, out, x, dif);
    // P2 interior (x0,y0 <= 4032): XCD-swizzled 1D grid; overwrites strips with final output.
    p2_diag<0><<<dim3(NP2), block, 0, stream>>>(ws16, out, out, x, dif);
}

// Round 23
// 131.272 us; speedup vs baseline: 1.2431x; 1.2431x over previous
//
#include <hip/hip_runtime.h>

#define N 4096
#define B 32
#define SST 66       // skew LDS row stride: 4-way scatter banks, b64-aligned conv reads
#define OST 34       // out-tile stride (overlaid on S)
#define SROWS 69     // logical skew rows -3..65 (band 0..62 consumed; 3 trash rows each side)
#define NP1 16641    // 129*129 P1 tiles  (= 8*2080+1)
#define Q1 2080
#define NP2 16129    // 127*127 P2 interior tiles (= 8*2016+1)
#define Q2 2016

// C(32,k) — binomial weights of (S+S^-1)^32; sum = 2^32 per pass.
__device__ constexpr float BIN32[33] = {
    1.f, 32.f, 496.f, 4960.f, 35960.f, 201376.f, 906192.f, 3365856.f,
    10518300.f, 28048800.f, 64512240.f, 129024480.f, 225792840.f,
    347373600.f, 471435600.f, 565722720.f, 601080390.f, 565722720.f,
    471435600.f, 347373600.f, 225792840.f, 129024480.f, 64512240.f,
    28048800.f, 10518300.f, 3365856.f, 906192.f, 201376.f, 35960.f,
    4960.f, 496.f, 32.f, 1.f};

// Bijective XCD-chunk swizzle (m204): HW assigns bid%8 -> XCD; each XCD owns a
// contiguous tile range so neighbor-tile halo re-reads hit the same per-XCD L2.
__device__ __forceinline__ int xcd_swz(int bid, int Q) {
    const int xcd = bid & 7;
    const int k = bid >> 3;
    return (xcd == 0) ? k : (Q + 1) + (xcd - 1) * Q + k;
}

// Half-sample mirror (replicate-pad iteration == free-space on this extension).
__device__ __forceinline__ int mir(int c) {
    c = (c < 0) ? (-1 - c) : c;
    return (c >= N) ? (2 * N - 1 - c) : c;
}

// bf16 RNE pack/unpack.
__device__ __forceinline__ unsigned short f2bf(float x) {
    unsigned b = __float_as_uint(x);
    b += 0x7FFFu + ((b >> 16) & 1u);
    return (unsigned short)(b >> 16);
}
__device__ __forceinline__ float bf2f(unsigned short u) {
    return __uint_as_float(((unsigned)u) << 16);
}

// Extended-t strips (tx>=4080 or ty>=4080) live in d_out (f32) at rows 64..128, cols <4064
// (disjoint from every P2-edge write, overwritten by P2-interior afterwards).
__device__ __forceinline__ size_t strip_off(int tx, int ty) {
    long e = (tx >= 4080) ? ((long)(ty + 16) * 32 + (tx - 4080))            // R1: 32x4128
                          : (132096L + (long)(ty - 4080) * (long)N + (tx + 16)); // R2: 4096x32
    return (size_t)(64 + e / 4064) * N + (size_t)(e % 4064);
}

// AO + modulate with precomputed diffuse (rx carries 2^64 deferred scale).
__device__ __forceinline__ float4 shade2(float4 v, float4 h, float4 df) {
    const float SC = 0x1p-64f;
    float4 o;
    o.x = df.x * (1.0f - fminf(fmaxf((v.x * SC - h.x) * 4.0f, 0.0f), 1.0f));
    o.y = df.y * (1.0f - fminf(fmaxf((v.y * SC - h.y) * 4.0f, 0.0f), 1.0f));
    o.z = df.z * (1.0f - fminf(fmaxf((v.z * SC - h.z) * 4.0f, 0.0f), 1.0f));
    o.w = df.w * (1.0f - fminf(fmaxf((v.w * SC - h.w) * 4.0f, 0.0f), 1.0f));
    return o;
}

// Chunked 33-tap conv on logical skew row d (phys row d+3): 2 chunks, 24-float windows.
__device__ __forceinline__ void conv33(const float* __restrict__ S, int rowAddr, float acc[8]) {
#pragma unroll
    for (int i = 0; i < 8; ++i) acc[i] = 0.f;
    {   // chunk 0: k = 0..15, window [0,24)
        float w[24];
#pragma unroll
        for (int j = 0; j < 12; ++j)
            *(float2*)&w[2 * j] = *(const float2*)&S[rowAddr + 2 * j];
#pragma unroll
        for (int k = 0; k < 16; ++k) {
            const float c = BIN32[k];
#pragma unroll
            for (int i = 0; i < 8; ++i) acc[i] = fmaf(c, w[i + k], acc[i]);
        }
    }
    {   // chunk 1: k = 16..32, window [16,40)
        float w[24];
#pragma unroll
        for (int j = 0; j < 12; ++j)
            *(float2*)&w[2 * j] = *(const float2*)&S[rowAddr + 16 + 2 * j];
#pragma unroll
        for (int k = 16; k <= 32; ++k) {
            const float c = BIN32[k];
#pragma unroll
            for (int i = 0; i < 8; ++i) acc[i] = fmaf(c, w[i + k - 16], acc[i]);
        }
    }
}

// ---------------- P1: anti-diagonal 33-tap pass + fused diffuse precompute ----------------
// Stage loads HOISTED: 4 independent global loads issued before any LDS scatter
// (one HBM round-trip instead of four serialized ones per thread).
__global__ __launch_bounds__(256, 8) void p1_antidiag(const float* __restrict__ src,
                                                      unsigned short* __restrict__ tcore,
                                                      float* __restrict__ tstrip,
                                                      const float* __restrict__ nrm,
                                                      unsigned short* __restrict__ dif) {
    __shared__ float S[SROWS * SST + 8];   // 18.2 KB; S2 overlaid after a barrier
    const int tile = xcd_swz((int)blockIdx.x, Q1);
    const int bx = tile % 129, by = tile / 129;
    const int X0 = 32 * bx - 16, Y0 = 32 * by - 16;   // t-tile origin (can be -16)
    const bool edgeT = (bx == 0) | (by == 0) | (bx == 128) | (by == 128);
    const int tid = (int)threadIdx.x;

    // ---- stage: issue all 4 loads, then scatter ----
    float4 vv[4];
    if (!edgeT) {
#pragma unroll
        for (int it = 0; it < 4; ++it) {
            const int m = tid + 256 * it;
            const int lyp = (m >> 4) - 16, lxp = 4 * (m & 15) - 16;
            vv[it] = *(const float4*)(src + (size_t)(Y0 + lyp) * N + (X0 + lxp));
        }
    } else {
#pragma unroll
        for (int it = 0; it < 4; ++it) {
            const int m = tid + 256 * it;
            const int lyp = (m >> 4) - 16, lxp = 4 * (m & 15) - 16;
            const float* row = src + (size_t)mir(Y0 + lyp) * N;
            vv[it] = make_float4(row[mir(X0 + lxp)], row[mir(X0 + lxp + 1)],
                                 row[mir(X0 + lxp + 2)], row[mir(X0 + lxp + 3)]);
        }
    }
#pragma unroll
    for (int it = 0; it < 4; ++it) {
        const int m = tid + 256 * it;
        const int lyp = (m >> 4) - 16, lxp = 4 * (m & 15) - 16;
        const int r0 = lxp + lyp;                 // logical skew row of v.x
        if (r0 >= -3 && r0 <= 62) {               // 4 bare stores; trash rows absorb edges
            const int base = (r0 + 3) * SST + (lxp + 16);
            S[base]                 = vv[it].x;
            S[base + (SST + 1)]     = vv[it].y;
            S[base + 2 * (SST + 1)] = vv[it].z;
            S[base + 3 * (SST + 1)] = vv[it].w;
        }
    }
    __syncthreads();

    // conv: thread (d=tid>>2, h=tid&3), taps contiguous in phys row d+3
    const int d = tid >> 2, h = tid & 3;
    const int lo = max(0, d - 31), hi = min(31, d);
    const int L = (lo & ~3) + 8 * h;
    const bool act = (d <= 62) && (L <= hi);
    float acc[8];
    if (act) conv33(S, (d + 3) * SST + L, acc);
    __syncthreads();                               // all S reads done; overlay S2

    float* SO = S;                                 // out-tile overlay
    if (act) {
#pragma unroll
        for (int i = 0; i < 8; ++i) {
            const int lx = L + i;
            if (lx >= lo && lx <= hi) SO[(d - lx) * OST + lx] = acc[i];
        }
    }
    __syncthreads();

    // writeback t
    {
        const int ly = tid >> 3, lx4 = tid & 7;
        const float2 v01 = *(const float2*)&SO[ly * OST + 4 * lx4];
        const float2 v23 = *(const float2*)&SO[ly * OST + 4 * lx4 + 2];
        const int wcol = X0 + 4 * lx4 + 16;   // tx+16
        const int wrow = Y0 + ly + 16;        // ty+16
        if (wcol < N && wrow < N) {
            ushort4 u;
            u.x = f2bf(v01.x); u.y = f2bf(v01.y); u.z = f2bf(v23.x); u.w = f2bf(v23.y);
            *(ushort4*)(tcore + (size_t)wrow * N + wcol) = u;
        } else {
            const int ty = Y0 + ly;
            const float vv2[4] = {v01.x, v01.y, v23.x, v23.y};
#pragma unroll
            for (int e = 0; e < 4; ++e) {
                const int tx = X0 + 4 * lx4 + e;
                tstrip[strip_off(tx, ty)] = vv2[e];
            }
        }
    }

    // diffuse tail: patch (32bx, 32by), bf16 -> dif
    if (bx < 128 && by < 128) {
        const int ly = tid >> 3, lx4 = tid & 7;
        const size_t dbase = (size_t)(32 * by + ly) * N + 32 * bx + 4 * lx4;
        const float L0 = 0.7053f, L1 = -0.7053f, L2 = 0.7053f;
        const float4 n0 = *(const float4*)(nrm + dbase);
        const float4 n1 = *(const float4*)(nrm + (size_t)N * N + dbase);
        const float4 n2 = *(const float4*)(nrm + 2 * (size_t)N * N + dbase);
        ushort4 u;
        u.x = f2bf(fmaxf(n0.x * L0 + n1.x * L1 + n2.x * L2, 0.0f) * 0.3f + 0.7f);
        u.y = f2bf(fmaxf(n0.y * L0 + n1.y * L1 + n2.y * L2, 0.0f) * 0.3f + 0.7f);
        u.z = f2bf(fmaxf(n0.z * L0 + n1.z * L1 + n2.z * L2, 0.0f) * 0.3f + 0.7f);
        u.w = f2bf(fmaxf(n0.w * L0 + n1.w * L1 + n2.w * L2, 0.0f) * 0.3f + 0.7f);
        *(ushort4*)(dif + dbase) = u;
    }
}

// ---------------- P2: diagonal 33-tap pass + fused shade (diffuse from bf16) ----------------
// STRIPS=0: interior tiles (1D grid, XCD-swizzled), stage loads hoisted; STRIPS=1: edge band.
template <int STRIPS>
__global__ __launch_bounds__(256, 8) void p2_diag(const unsigned short* __restrict__ tcore,
                                                  const float* __restrict__ tstrip,
                                                  float* __restrict__ dst,
                                                  const float* __restrict__ xin,
                                                  const unsigned short* __restrict__ dif) {
    __shared__ float S[SROWS * SST + 8];
    int X0, Y0;
    if constexpr (STRIPS) {
        if (blockIdx.y == 0) { X0 = 4064; Y0 = 32 * (int)blockIdx.x; }
        else                 { X0 = 32 * (int)blockIdx.x; Y0 = 4064; }
    } else {
        const int tile = xcd_swz((int)blockIdx.x, Q2);
        X0 = 32 * (tile % 127); Y0 = 32 * (tile / 127);
    }
    const int tid = (int)threadIdx.x;

    if constexpr (!STRIPS) {
        // ---- stage: issue all 4 bf16 loads, then scatter ----
        ushort4 uu[4];
#pragma unroll
        for (int it = 0; it < 4; ++it) {
            const int m = tid + 256 * it;
            const int lyp = (m >> 4) - 16, lxp = 4 * (m & 15) - 16;
            uu[it] = *(const ushort4*)(tcore + (size_t)(Y0 + lyp + 16) * N + (X0 + lxp + 16));
        }
#pragma unroll
        for (int it = 0; it < 4; ++it) {
            const int m = tid + 256 * it;
            const int lyp = (m >> 4) - 16, lxp = 4 * (m & 15) - 16;
            const int r0 = lxp - lyp + 31;        // logical skew row of v.x
            if (r0 >= -3 && r0 <= 62) {
                const int base = (r0 + 3) * SST + (lxp + 16);
                S[base]                 = bf2f(uu[it].x);
                S[base + (SST + 1)]     = bf2f(uu[it].y);
                S[base + 2 * (SST + 1)] = bf2f(uu[it].z);
                S[base + 3 * (SST + 1)] = bf2f(uu[it].w);
            }
        }
    } else {
        for (int m = tid; m < 64 * 16; m += 256) {
            const int ly = m >> 4, lx4 = m & 15;
            const int lyp = ly - 16, lxp = 4 * lx4 - 16;
            const int ty = Y0 + lyp;
            float tmp[4];
#pragma unroll
            for (int e = 0; e < 4; ++e) {
                const int tx = X0 + lxp + e;
                tmp[e] = (tx < 4080 && ty < 4080)
                             ? bf2f(tcore[(size_t)(ty + 16) * N + (tx + 16)])
                             : tstrip[strip_off(tx, ty)];
            }
            const int r0 = lxp - lyp + 31;
            if (r0 >= -3 && r0 <= 62) {
                const int base = (r0 + 3) * SST + (lxp + 16);
                S[base]                 = tmp[0];
                S[base + (SST + 1)]     = tmp[1];
                S[base + 2 * (SST + 1)] = tmp[2];
                S[base + 3 * (SST + 1)] = tmp[3];
            }
        }
    }
    __syncthreads();

    const int d = tid >> 2, h = tid & 3;
    const int lo = max(0, d - 31), hi = min(31, d);
    const int L = (lo & ~3) + 8 * h;
    const bool act = (d <= 62) && (L <= hi);
    float acc[8];
    if (act) conv33(S, (d + 3) * SST + L, acc);
    __syncthreads();

    float* SO = S;
    if (act) {
#pragma unroll
        for (int i = 0; i < 8; ++i) {
            const int lx = L + i;
            if (lx >= lo && lx <= hi) SO[(lx - d + 31) * OST + lx] = acc[i];
        }
    }
    __syncthreads();

    // writeback + fused shade (always in-bounds)
    {
        const int ly = tid >> 3, lx4 = tid & 7;
        const float2 v01 = *(const float2*)&SO[ly * OST + 4 * lx4];
        const float2 v23 = *(const float2*)&SO[ly * OST + 4 * lx4 + 2];
        const float4 v = make_float4(v01.x, v01.y, v23.x, v23.y);
        const size_t base = (size_t)(Y0 + ly) * N + X0 + 4 * lx4;
        const float4 h4 = *(const float4*)(xin + base);
        const ushort4 ud = *(const ushort4*)(dif + base);
        const float4 df = make_float4(bf2f(ud.x), bf2f(ud.y), bf2f(ud.z), bf2f(ud.w));
        *(float4*)(dst + base) = shade2(v, h4, df);
    }
}

extern "C" void kernel_launch(void* const* d_in, const int* in_sizes, int n_in,
                              void* d_out, int out_size, void* d_ws, size_t ws_size,
                              hipStream_t stream) {
    const float* x       = (const float*)d_in[0];
    const float* normals = (const float*)d_in[1];
    float* out = (float*)d_out;
    unsigned short* ws16 = (unsigned short*)d_ws;       // t core (bf16, 32 MB)
    unsigned short* dif  = ws16 + (size_t)N * N;        // diffuse (bf16, 32 MB)

    dim3 block(256);

    // P1: t on [-16,4112)^2 (mirror-extended) + diffuse precompute. XCD-swizzled 1D grid.
    p1_antidiag<<<dim3(NP1), block, 0, stream>>>(x, ws16, out, normals, dif);
    // P2 edge band (x0=4064 or y0=4064): strip-aware reads; writes only cols>=4064 / rows>=4064.
    p2_diag<1><<<dim3(128, 2), block, 0, stream>>>(ws16, out, out, x, dif);
    // P2 interior (x0,y0 <= 4032): XCD-swizzled 1D grid; overwrites strips with final output.
    p2_diag<0><<<dim3(NP2), block, 0, stream>>>(ws16, out, out, x, dif);
}